// Round 21
// baseline (227.789 us; speedup 1.0000x reference)
//
#include <hip/hip_runtime.h>

// Problem constants (fixed by the reference)
#define NN    100000   // nodes
#define NE    3200000  // edges
#define DIMK  256      // feature dim
#define NC    32       // classes
#define NG    64       // graphs

#define ROWS   64      // nodes per src-bucket
#define NBUCK  1563    // ceil(NN/64)
#define CAP    2432    // per-bucket record capacity (mean 2047, sigma ~45 -> +8.5 sigma)
#define NB1    512     // edge chunks for bucketing (NE/NB1 = 6250 exact)
#define EPB    6250    // edges per bucketing block
#define NSL    16      // reduce slices
#define MAXG   512     // cap on k_fused blocks (2/CU)

// Workspace layout (bytes). Fixed region = 16.66 MB; partials sized from ws.
// nodeinfo/cnt/exc overlay the FRONT of the partial region (dead before k_fused).
static constexpr size_t OFF_REC    = 0;           // [NBUCK*CAP] u32 = 15,204,864
                                                  // (first 12.8 MB doubles as deg partials)
static constexpr size_t OFF_DINV   = 15204864;    // [NN] f32 = 400,000
static constexpr size_t OFF_BTOT   = 15604864;    // [NBUCK] int (pad 8192)
static constexpr size_t OFF_START  = 15613056;    // [NG+1] int (pad 512)
static constexpr size_t OFF_CTRL   = 15613568;    // int[32] (pad 128)
static constexpr size_t OFF_P2     = 15613696;    // [NSL][NG*DIMK] f32 = 1,048,576
static constexpr size_t OFF_PART   = 16662272;    // [grid][NG*DIMK] f32 (64 KB each)
// overlays (dead before k_fused writes partials):
static constexpr size_t OFF_NODEI  = OFF_PART;              // [NN] u32: (deg<<6)|batch
static constexpr size_t OFF_CNT    = OFF_PART + 400000;     // [NBUCK*NB1] int = 3,201,024
static constexpr size_t OFF_EXC    = OFF_PART + 3601024;    // [NBUCK*NB1] int (ends +6.8MB)

__device__ __forceinline__ int idx_at(const void* p, long i, bool i64) {
    return i64 ? (int)((const long long*)p)[i] : ((const int*)p)[i];
}

// int64 vs int32: high words of the first int64 entries are all zero.
// For genuine int32 src indices in [0,100000), P(false positive) ~ 1e-30.
__device__ __forceinline__ bool detect_i64(const void* ei) {
    const int* w = (const int*)ei;
    return (w[1] == 0) & (w[3] == 0) & (w[5] == 0) &
           (w[7] == 0) & (w[9] == 0) & (w[11] == 0);
}

// Merged edge pass 1.
// Blocks 0..255: degree histogram halves (u8 LDS counters; max deg ~70 << 255).
// Blocks 256..767: per-(bucket,chunk) counts via LDS counters.
__global__ __launch_bounds__(256) void k_pre(const void* __restrict__ ei,
        unsigned int* __restrict__ parts, int* __restrict__ cnt) {
    __shared__ unsigned int h[12500];   // 50 KB
    const bool i64 = detect_i64(ei);
    const int b = blockIdx.x;
    if (b < 256) {
        const int hh = b >> 7;
        const int sl = b & 127;
        const int lo = hh * 50000, hi = lo + 50000;
        for (int t = threadIdx.x; t < 12500; t += 256) h[t] = 0u;
        __syncthreads();
        const int e0 = sl * 25000;
        for (int e = e0 + threadIdx.x; e < e0 + 25000; e += 256) {
            int d = idx_at(ei, (long)NE + e, i64);
            if (d >= lo && d < hi) {
                int r = d - lo;
                atomicAdd(&h[r >> 2], 1u << ((r & 3) * 8));
            }
        }
        __syncthreads();
        for (int t = threadIdx.x; t < 12500; t += 256)
            parts[(size_t)b * 12500 + t] = h[t];
    } else {
        const int k = b - 256;          // 0..511
        for (int t = threadIdx.x; t < NBUCK; t += 256) h[t] = 0u;
        __syncthreads();
        const int e0 = k * EPB;
        for (int e = e0 + threadIdx.x; e < e0 + EPB; e += 256) {
            int s = idx_at(ei, e, i64);
            atomicAdd(&h[s >> 6], 1u);
        }
        __syncthreads();
        for (int t = threadIdx.x; t < NBUCK; t += 256)
            cnt[t * NB1 + k] = (int)h[t];
    }
}

// Merged node/offset pass (512 threads).
// Blocks 0..48: degree reduce -> dinv AND nodeinfo = (deg<<6)|batch[node].
// Blocks 49..244: graph start offsets from sorted batch.
// Blocks 245..1807: per-bucket exclusive scan of its 512 chunk counts.
__global__ __launch_bounds__(512) void k_mid(const unsigned int* __restrict__ parts,
        unsigned int* __restrict__ nodeinfo, float* __restrict__ dinv,
        const void* __restrict__ batch, const void* __restrict__ ei,
        int* __restrict__ start, const int* __restrict__ cnt,
        int* __restrict__ exc, int* __restrict__ btot) {
    __shared__ int s[512];
    const int b = blockIdx.x;
    const int t = threadIdx.x;
    if (b < 49) {
        const bool i64 = detect_i64(ei);
        int i = b * 512 + t;            // word index 0..24999
        if (i >= 25000) return;
        int h = (i >= 12500) ? 1 : 0;
        int w = i - h * 12500;
        int c0 = 0, c1 = 0, c2 = 0, c3 = 0;
        const unsigned int* base = parts + (size_t)(h * 128) * 12500 + w;
#pragma unroll 4
        for (int q = 0; q < 128; ++q) {
            unsigned int v = base[(size_t)q * 12500];
            c0 += v & 255u; c1 += (v >> 8) & 255u; c2 += (v >> 16) & 255u; c3 += v >> 24;
        }
        int node = h * 50000 + w * 4;
        dinv[node]     = 1.0f / sqrtf((float)(1 + c0));
        dinv[node + 1] = 1.0f / sqrtf((float)(1 + c1));
        dinv[node + 2] = 1.0f / sqrtf((float)(1 + c2));
        dinv[node + 3] = 1.0f / sqrtf((float)(1 + c3));
        nodeinfo[node]     = ((unsigned)(1 + c0) << 6) | (unsigned)idx_at(batch, node, i64);
        nodeinfo[node + 1] = ((unsigned)(1 + c1) << 6) | (unsigned)idx_at(batch, node + 1, i64);
        nodeinfo[node + 2] = ((unsigned)(1 + c2) << 6) | (unsigned)idx_at(batch, node + 2, i64);
        nodeinfo[node + 3] = ((unsigned)(1 + c3) << 6) | (unsigned)idx_at(batch, node + 3, i64);
    } else if (b < 245) {
        const bool i64 = detect_i64(ei);
        int i = (b - 49) * 512 + t;
        if (i >= NN) return;
        int bi = idx_at(batch, i, i64);
        int bp = (i == 0) ? -1 : idx_at(batch, i - 1, i64);
        for (int g = bp + 1; g <= bi; ++g) start[g] = i;
        if (i == NN - 1)
            for (int g = bi + 1; g <= NG; ++g) start[g] = NN;
    } else {
        const int bkt = b - 245;        // 0..1562
        int v = cnt[bkt * NB1 + t];
        s[t] = v;
        __syncthreads();
        for (int off = 1; off < 512; off <<= 1) {
            int u = (t >= off) ? s[t - off] : 0;
            __syncthreads();
            s[t] += u;
            __syncthreads();
        }
        exc[bkt * NB1 + t] = bkt * CAP + (s[t] - v);
        if (t == 511) btot[bkt] = s[511];
    }
}

// Place 4-byte edge records: (deg[dst] << 12) | (batch[dst]*64 + (src&63)).
// ONE random 4B gather per edge (nodeinfo fuses deg+batch).
// TRANSPOSED A index (graph-major). Also zeroes the k_fused work counter.
__global__ __launch_bounds__(256) void k_place(const void* __restrict__ ei,
        const unsigned int* __restrict__ nodeinfo,
        const int* __restrict__ exc, unsigned int* __restrict__ rec,
        int* __restrict__ ctrl) {
    __shared__ unsigned int lc[NBUCK];
    __shared__ int lbase[NBUCK];
    const bool i64 = detect_i64(ei);
    const int k = blockIdx.x;
    if (k == 0 && threadIdx.x == 0) ctrl[1] = 0;
    for (int t = threadIdx.x; t < NBUCK; t += 256) {
        lc[t] = 0u;
        lbase[t] = exc[t * NB1 + k];
    }
    __syncthreads();
    const int e0 = k * EPB;
    for (int e = e0 + threadIdx.x; e < e0 + EPB; e += 256) {
        int s = idx_at(ei, e, i64);
        int d = idx_at(ei, (long)NE + e, i64);
        unsigned int ni = nodeinfo[d];
        unsigned int deg = min(ni >> 6, 1048575u);
        unsigned int g = ni & 63u;
        int b = s >> 6;
        unsigned int r = atomicAdd(&lc[b], 1u);
        rec[lbase[b] + (int)r] = (deg << 12) | (g * 64 + (unsigned)(s & 63));
    }
}

// Fused persistent kernel (r21 = r19 + per-8-row-group __syncthreads in the
// FMA loop). Diagnosis r12-r20: 8 waves/block read the SAME x rows -> 8x read
// amplification (8KB/row/block) hits the L2/L3 BW wall at ~50% VALUBusy,
// independent of occupancy (r16: 73% occ / 28% VALU; r20: 58% / 45%). The
// group barrier (a) keeps all 8 waves inside an 8-row window so 7/8 of the
// reads hit the 32KB L1, and (b) drains vmcnt, forcing the 8-deep prefetch
// buffer to be truly live (r14: compiler re-sank the loads, VGPR 56).
// Cost: 8 barriers/bucket ~ 400cy vs 5400cy FMA.
__global__ __launch_bounds__(512, 2) void k_fused(
        const float* __restrict__ x, const float* __restrict__ dinv,
        const void* __restrict__ batch, const void* __restrict__ ei,
        const unsigned int* __restrict__ rec, const int* __restrict__ btot,
        float* __restrict__ part, int* __restrict__ ctrl) {
    __shared__ __align__(16) float Ach[64 * ROWS];    // 16 KB, [graph][row]
    __shared__ int sbkt;
    const bool i64 = detect_i64(ei);
    const int tid  = threadIdx.x;
    const int gi   = tid >> 6;     // wave id = graph group 0..7
    const int lane = tid & 63;     // row for areg; features lane*4..+4 for x

    float acc[8][4];
#pragma unroll
    for (int g = 0; g < 8; ++g)
#pragma unroll
        for (int d = 0; d < 4; ++d) acc[g][d] = 0.0f;

    const float4* x4 = (const float4*)x;
    float4* Ach4 = (float4*)Ach;
    const float4 z4 = make_float4(0.f, 0.f, 0.f, 0.f);
    const int jmax = NN - 1;

    for (;;) {
        if (tid == 0) sbkt = atomicAdd(&ctrl[1], 1);
        __syncthreads();
        const int bkt = sbkt;
        if (bkt >= NBUCK) break;
        const int j0 = bkt * ROWS;

        // zero Ach (conflict-free linear float4)
        Ach4[tid] = z4;
        Ach4[tid + 512] = z4;
        __syncthreads();
        // seed self-loop: Ach[batch[j]][r] = dinv[j]; areg scale -> dinv^2
        if (tid < ROWS) {
            int j = j0 + tid;
            if (j < NN) Ach[idx_at(batch, j, i64) * 64 + tid] = dinv[j];
        }
        __syncthreads();
        // replay edge records into Ach via LDS atomics (index = g*64+row)
        {
            const int rb = bkt * CAP;
            const int re = rb + btot[bkt];
            for (int r = rb + tid; r < re; r += 512) {
                unsigned int q = rec[r];
                float val = 1.0f / sqrtf((float)(q >> 12));   // == dinv[dst] bits
                atomicAdd(&Ach[q & 4095u], val);
            }
        }
        __syncthreads();
        // pull A into registers (fused dinv[src] row scale); coalesced reads
        float areg[8];
        {
            float dv = dinv[min(j0 + lane, jmax)];   // pad rows: A is 0 anyway
#pragma unroll
            for (int q = 0; q < 8; ++q)
                areg[q] = Ach[(gi * 8 + q) * 64 + lane] * dv;
        }
        __syncthreads();   // all areg reads done -> Ach reusable next bucket

        if (bkt < NBUCK - 1) {
            // FAST path: rows j0..j0+63 valid; over-read stays < NN.
            const float4* xp = x4 + (size_t)j0 * 64 + lane;
            float4 buf[8];
#pragma unroll
            for (int k = 0; k < 8; ++k) buf[k] = xp[k * 64];
            xp += 512;
            for (int c = 0; c < 8; ++c) {        // 8 groups of 8 rows
#pragma unroll
                for (int jj = 0; jj < 8; ++jj) {
                    float4 xv = buf[jj];
                    buf[jj] = xp[jj * 64];       // reissue slot 8 rows ahead
#pragma unroll
                    for (int q = 0; q < 8; ++q) {
                        float aq = __int_as_float(__builtin_amdgcn_readlane(
                            __float_as_int(areg[q]), c * 8 + jj));
                        acc[q][0] = fmaf(aq, xv.x, acc[q][0]);
                        acc[q][1] = fmaf(aq, xv.y, acc[q][1]);
                        acc[q][2] = fmaf(aq, xv.z, acc[q][2]);
                        acc[q][3] = fmaf(aq, xv.w, acc[q][3]);
                    }
                }
                xp += 512;
                // Lockstep the 8 waves (L1 reuse window) AND force the
                // prefetch loads complete (vmcnt drained at barrier).
                __syncthreads();
            }
        } else {
            // TAIL bucket (one per grid): clamped depth-1 loop.
            float4 xv = x4[(size_t)min(j0, jmax) * 64 + lane];
#pragma unroll 4
            for (int jj = 0; jj < ROWS; ++jj) {
                float4 xn = x4[(size_t)min(j0 + jj + 1, jmax) * 64 + lane];
#pragma unroll
                for (int q = 0; q < 8; ++q) {
                    float aq = __int_as_float(__builtin_amdgcn_readlane(
                        __float_as_int(areg[q]), jj));
                    acc[q][0] = fmaf(aq, xv.x, acc[q][0]);
                    acc[q][1] = fmaf(aq, xv.y, acc[q][1]);
                    acc[q][2] = fmaf(aq, xv.z, acc[q][2]);
                    acc[q][3] = fmaf(aq, xv.w, acc[q][3]);
                }
                xv = xn;
            }
        }
    }

    // write block partial: graphs gi*8..+8, features lane*4..+4 (all static)
    float* p = part + (size_t)blockIdx.x * (NG * DIMK);
#pragma unroll
    for (int g = 0; g < 8; ++g) {
        float4 w = make_float4(acc[g][0], acc[g][1], acc[g][2], acc[g][3]);
        ((float4*)(p + (gi * 8 + g) * DIMK))[lane] = w;
    }
}

// Split-K reduce stage 1: NSL slices x 4096 float4 cols, coalesced.
__global__ __launch_bounds__(256) void k_reduce1(const float4* __restrict__ part,
        float4* __restrict__ p2, int nblk) {
    int id = blockIdx.x * 256 + threadIdx.x;   // 0..65535
    int c4 = id & 4095;
    int sl = id >> 12;
    int span = (nblk + NSL - 1) / NSL;
    int b0 = sl * span, b1 = min(b0 + span, nblk);
    float4 s = make_float4(0.f, 0.f, 0.f, 0.f);
    for (int b = b0; b < b1; ++b) {
        float4 v = part[(size_t)b * 4096 + c4];
        s.x += v.x; s.y += v.y; s.z += v.z; s.w += v.w;
    }
    p2[(size_t)sl * 4096 + c4] = s;
}

// Final: fold NSL slices into S (LDS), then S @ W / cnt + bias.
__global__ __launch_bounds__(256) void k_final(const float* __restrict__ p2,
        const float* __restrict__ W, const float* __restrict__ bias,
        const int* __restrict__ start, float* __restrict__ out) {
    __shared__ float Sb[8 * DIMK];   // 8 KB
    const int tid = threadIdx.x, b = blockIdx.x;
    for (int t = tid; t < 8 * DIMK; t += 256) {
        int gl = t >> 8, d = t & 255;
        float s = 0.f;
#pragma unroll
        for (int sl = 0; sl < NSL; ++sl)
            s += p2[(size_t)sl * (NG * DIMK) + (b * 8 + gl) * DIMK + d];
        Sb[t] = s;
    }
    __syncthreads();
    int g = tid >> 5, c = tid & 31;
    float sum = 0.f;
#pragma unroll 8
    for (int d = 0; d < DIMK; ++d)
        sum = fmaf(Sb[g * DIMK + d], W[d * NC + c], sum);
    int gg = b * 8 + g;
    float cn = (float)max(start[gg + 1] - start[gg], 1);
    out[gg * NC + c] = sum / cn + bias[c];
}

extern "C" void kernel_launch(void* const* d_in, const int* in_sizes, int n_in,
                              void* d_out, int out_size, void* d_ws, size_t ws_size,
                              hipStream_t stream) {
    const float* x    = (const float*)d_in[0];
    const float* W    = (const float*)d_in[1];
    const float* bias = (const float*)d_in[2];
    const void*  ei   = d_in[3];
    const void*  batch= d_in[4];
    float* out = (float*)d_out;

    char* ws = (char*)d_ws;
    unsigned int* rec  = (unsigned int*)(ws + OFF_REC);
    unsigned int* degp = (unsigned int*)(ws + OFF_REC);    // overlay (dead before rec)
    float* dinv  = (float*)(ws + OFF_DINV);
    int*   btot  = (int*)(ws + OFF_BTOT);
    int*   start = (int*)(ws + OFF_START);
    int*   ctrl  = (int*)(ws + OFF_CTRL);
    float* p2    = (float*)(ws + OFF_P2);
    float* part  = (float*)(ws + OFF_PART);
    // overlays inside part region (dead before k_fused writes partials):
    unsigned int* nodeinfo = (unsigned int*)(ws + OFF_NODEI);
    int*   cnt   = (int*)(ws + OFF_CNT);
    int*   exc   = (int*)(ws + OFF_EXC);

    // grid sized to workspace (ws in [43.5, 54.6) MB -> grid ~410-512)
    long avail = (long)(ws_size - OFF_PART) / 65536;
    int grid = (int)avail;
    if (grid > MAXG) grid = MAXG;
    if (grid < 64) grid = 64;

    k_pre    <<<768, 256, 0, stream>>>(ei, degp, cnt);
    k_mid    <<<1808, 512, 0, stream>>>(degp, nodeinfo, dinv, batch, ei, start,
                                        cnt, exc, btot);
    k_place  <<<NB1, 256, 0, stream>>>(ei, nodeinfo, exc, rec, ctrl);
    k_fused  <<<grid, 512, 0, stream>>>(x, dinv, batch, ei, rec, btot, part, ctrl);
    k_reduce1<<<256, 256, 0, stream>>>((const float4*)part, (float4*)p2, grid);
    k_final  <<<8, 256, 0, stream>>>(p2, W, bias, start, out);
}

// Round 22
// 219.217 us; speedup vs baseline: 1.0391x; 1.0391x over previous
//
#include <hip/hip_runtime.h>

// Problem constants (fixed by the reference)
#define NN    100000   // nodes
#define NE    3200000  // edges
#define DIMK  256      // feature dim
#define NC    32       // classes
#define NG    64       // graphs

#define ROWS   64      // nodes per src-bucket
#define NBUCK  1563    // ceil(NN/64)
#define CAP    2432    // per-bucket record capacity (mean 2047, sigma ~45 -> +8.5 sigma)
#define NB1    512     // edge chunks for bucketing (NE/NB1 = 6250 exact)
#define EPB    6250    // edges per bucketing block
#define MAXG   512     // cap on k_fused blocks (2/CU)

// Workspace layout (bytes). Fixed region = 16.66 MB; partials sized from ws.
// nodeinfo/cnt/exc overlay the FRONT of the partial region (dead before k_fused).
static constexpr size_t OFF_REC    = 0;           // [NBUCK*CAP] u32 = 15,204,864
                                                  // (first 12.8 MB doubles as deg partials)
static constexpr size_t OFF_DINV   = 15204864;    // [NN] f32 = 400,000
static constexpr size_t OFF_BTOT   = 15604864;    // [NBUCK] int (pad 8192)
static constexpr size_t OFF_START  = 15613056;    // [NG+1] int (pad 512)
static constexpr size_t OFF_CTRL   = 15613568;    // int[32] (pad 128)
static constexpr size_t OFF_P2     = 15613696;    // (spare) 1 MB
static constexpr size_t OFF_PART   = 16662272;    // [grid][NG*DIMK] f32 (64 KB each)
// overlays (dead before k_fused writes partials):
static constexpr size_t OFF_NODEI  = OFF_PART;              // [NN] u32: (deg<<6)|batch
static constexpr size_t OFF_CNT    = OFF_PART + 400000;     // [NBUCK*NB1] int = 3,201,024
static constexpr size_t OFF_EXC    = OFF_PART + 3601024;    // [NBUCK*NB1] int (ends +6.8MB)

__device__ __forceinline__ int idx_at(const void* p, long i, bool i64) {
    return i64 ? (int)((const long long*)p)[i] : ((const int*)p)[i];
}

// int64 vs int32: high words of the first int64 entries are all zero.
// For genuine int32 src indices in [0,100000), P(false positive) ~ 1e-30.
__device__ __forceinline__ bool detect_i64(const void* ei) {
    const int* w = (const int*)ei;
    return (w[1] == 0) & (w[3] == 0) & (w[5] == 0) &
           (w[7] == 0) & (w[9] == 0) & (w[11] == 0);
}

// Merged edge pass 1.
// Blocks 0..255: degree histogram halves (u8 LDS counters; max deg ~70 << 255).
// Blocks 256..767: per-(bucket,chunk) counts via LDS counters.
__global__ __launch_bounds__(256) void k_pre(const void* __restrict__ ei,
        unsigned int* __restrict__ parts, int* __restrict__ cnt) {
    __shared__ unsigned int h[12500];   // 50 KB
    const bool i64 = detect_i64(ei);
    const int b = blockIdx.x;
    if (b < 256) {
        const int hh = b >> 7;
        const int sl = b & 127;
        const int lo = hh * 50000, hi = lo + 50000;
        for (int t = threadIdx.x; t < 12500; t += 256) h[t] = 0u;
        __syncthreads();
        const int e0 = sl * 25000;
        for (int e = e0 + threadIdx.x; e < e0 + 25000; e += 256) {
            int d = idx_at(ei, (long)NE + e, i64);
            if (d >= lo && d < hi) {
                int r = d - lo;
                atomicAdd(&h[r >> 2], 1u << ((r & 3) * 8));
            }
        }
        __syncthreads();
        for (int t = threadIdx.x; t < 12500; t += 256)
            parts[(size_t)b * 12500 + t] = h[t];
    } else {
        const int k = b - 256;          // 0..511
        for (int t = threadIdx.x; t < NBUCK; t += 256) h[t] = 0u;
        __syncthreads();
        const int e0 = k * EPB;
        for (int e = e0 + threadIdx.x; e < e0 + EPB; e += 256) {
            int s = idx_at(ei, e, i64);
            atomicAdd(&h[s >> 6], 1u);
        }
        __syncthreads();
        for (int t = threadIdx.x; t < NBUCK; t += 256)
            cnt[t * NB1 + k] = (int)h[t];
    }
}

// Merged node/offset pass (512 threads).
// Blocks 0..48: degree reduce -> dinv AND nodeinfo = (deg<<6)|batch[node].
// Blocks 49..244: graph start offsets from sorted batch.
// Blocks 245..1807: per-bucket exclusive scan of its 512 chunk counts.
__global__ __launch_bounds__(512) void k_mid(const unsigned int* __restrict__ parts,
        unsigned int* __restrict__ nodeinfo, float* __restrict__ dinv,
        const void* __restrict__ batch, const void* __restrict__ ei,
        int* __restrict__ start, const int* __restrict__ cnt,
        int* __restrict__ exc, int* __restrict__ btot) {
    __shared__ int s[512];
    const int b = blockIdx.x;
    const int t = threadIdx.x;
    if (b < 49) {
        const bool i64 = detect_i64(ei);
        int i = b * 512 + t;            // word index 0..24999
        if (i >= 25000) return;
        int h = (i >= 12500) ? 1 : 0;
        int w = i - h * 12500;
        int c0 = 0, c1 = 0, c2 = 0, c3 = 0;
        const unsigned int* base = parts + (size_t)(h * 128) * 12500 + w;
#pragma unroll 4
        for (int q = 0; q < 128; ++q) {
            unsigned int v = base[(size_t)q * 12500];
            c0 += v & 255u; c1 += (v >> 8) & 255u; c2 += (v >> 16) & 255u; c3 += v >> 24;
        }
        int node = h * 50000 + w * 4;
        dinv[node]     = 1.0f / sqrtf((float)(1 + c0));
        dinv[node + 1] = 1.0f / sqrtf((float)(1 + c1));
        dinv[node + 2] = 1.0f / sqrtf((float)(1 + c2));
        dinv[node + 3] = 1.0f / sqrtf((float)(1 + c3));
        nodeinfo[node]     = ((unsigned)(1 + c0) << 6) | (unsigned)idx_at(batch, node, i64);
        nodeinfo[node + 1] = ((unsigned)(1 + c1) << 6) | (unsigned)idx_at(batch, node + 1, i64);
        nodeinfo[node + 2] = ((unsigned)(1 + c2) << 6) | (unsigned)idx_at(batch, node + 2, i64);
        nodeinfo[node + 3] = ((unsigned)(1 + c3) << 6) | (unsigned)idx_at(batch, node + 3, i64);
    } else if (b < 245) {
        const bool i64 = detect_i64(ei);
        int i = (b - 49) * 512 + t;
        if (i >= NN) return;
        int bi = idx_at(batch, i, i64);
        int bp = (i == 0) ? -1 : idx_at(batch, i - 1, i64);
        for (int g = bp + 1; g <= bi; ++g) start[g] = i;
        if (i == NN - 1)
            for (int g = bi + 1; g <= NG; ++g) start[g] = NN;
    } else {
        const int bkt = b - 245;        // 0..1562
        int v = cnt[bkt * NB1 + t];
        s[t] = v;
        __syncthreads();
        for (int off = 1; off < 512; off <<= 1) {
            int u = (t >= off) ? s[t - off] : 0;
            __syncthreads();
            s[t] += u;
            __syncthreads();
        }
        exc[bkt * NB1 + t] = bkt * CAP + (s[t] - v);
        if (t == 511) btot[bkt] = s[511];
    }
}

// Place 4-byte edge records: (deg[dst] << 12) | (batch[dst]*64 + (src&63)).
// ONE random 4B gather per edge (nodeinfo fuses deg+batch).
// TRANSPOSED A index (graph-major). Also zeroes the k_fused work counter.
__global__ __launch_bounds__(256) void k_place(const void* __restrict__ ei,
        const unsigned int* __restrict__ nodeinfo,
        const int* __restrict__ exc, unsigned int* __restrict__ rec,
        int* __restrict__ ctrl) {
    __shared__ unsigned int lc[NBUCK];
    __shared__ int lbase[NBUCK];
    const bool i64 = detect_i64(ei);
    const int k = blockIdx.x;
    if (k == 0 && threadIdx.x == 0) ctrl[1] = 0;
    for (int t = threadIdx.x; t < NBUCK; t += 256) {
        lc[t] = 0u;
        lbase[t] = exc[t * NB1 + k];
    }
    __syncthreads();
    const int e0 = k * EPB;
    for (int e = e0 + threadIdx.x; e < e0 + EPB; e += 256) {
        int s = idx_at(ei, e, i64);
        int d = idx_at(ei, (long)NE + e, i64);
        unsigned int ni = nodeinfo[d];
        unsigned int deg = min(ni >> 6, 1048575u);
        unsigned int g = ni & 63u;
        int b = s >> 6;
        unsigned int r = atomicAdd(&lc[b], 1u);
        rec[lbase[b] + (int)r] = (deg << 12) | (g * 64 + (unsigned)(s & 63));
    }
}

// Fused persistent kernel (r22): 4 GRAPH-GROUPS x 2 ROW-HALVES wave mapping.
// Wave w: q=w&3 -> graphs q*16..+16 (acc[16][4], areg[16]); rh=w>>2 -> rows
// rh*32..+32. Each x-row is read by 4 waves instead of 8 -> block x-traffic
// halves (~820 -> ~410 MB through L3; r19 at 9 TB/s was plausibly L3-BW-
// bound). FMA loop keeps the barrier-free r19 pointer-prefetch form; the two
// row-halves combine ONCE per block lifetime via 16 static-g LDS rounds
// (r17-proven). launch_bounds(512,2) = min 2 BLOCKS/CU -> VGPR cap 128.
__global__ __launch_bounds__(512, 2) void k_fused(
        const float* __restrict__ x, const float* __restrict__ dinv,
        const void* __restrict__ batch, const void* __restrict__ ei,
        const unsigned int* __restrict__ rec, const int* __restrict__ btot,
        float* __restrict__ part, int* __restrict__ ctrl) {
    __shared__ __align__(16) float Ach[64 * ROWS];    // 16 KB, [graph][row]
    __shared__ int sbkt;
    const bool i64 = detect_i64(ei);
    const int tid  = threadIdx.x;
    const int w    = tid >> 6;     // wave 0..7
    const int q    = w & 3;        // graph group: graphs q*16 .. +16
    const int rh   = w >> 2;       // row half: rows rh*32 .. +32
    const int lane = tid & 63;     // areg row; feature float4 col
    const int rbase = rh << 5;     // 0 or 32 (wave-uniform)

    float acc[16][4];
#pragma unroll
    for (int g = 0; g < 16; ++g)
#pragma unroll
        for (int d = 0; d < 4; ++d) acc[g][d] = 0.0f;

    const float4* x4 = (const float4*)x;
    float4* Ach4 = (float4*)Ach;
    const float4 z4 = make_float4(0.f, 0.f, 0.f, 0.f);
    const int jmax = NN - 1;

    for (;;) {
        if (tid == 0) sbkt = atomicAdd(&ctrl[1], 1);
        __syncthreads();
        const int bkt = sbkt;
        if (bkt >= NBUCK) break;
        const int j0 = bkt * ROWS;

        // zero Ach (conflict-free linear float4)
        Ach4[tid] = z4;
        Ach4[tid + 512] = z4;
        __syncthreads();
        // seed self-loop: Ach[batch[j]][r] = dinv[j]; areg scale -> dinv^2
        if (tid < ROWS) {
            int j = j0 + tid;
            if (j < NN) Ach[idx_at(batch, j, i64) * 64 + tid] = dinv[j];
        }
        __syncthreads();
        // replay edge records into Ach via LDS atomics (index = g*64+row)
        {
            const int rb = bkt * CAP;
            const int re = rb + btot[bkt];
            for (int r = rb + tid; r < re; r += 512) {
                unsigned int qq = rec[r];
                float val = 1.0f / sqrtf((float)(qq >> 12));   // == dinv[dst] bits
                atomicAdd(&Ach[qq & 4095u], val);
            }
        }
        __syncthreads();
        // pull A into registers: lane holds row `lane`'s 16 graph-values of
        // group q, scaled by dinv[row]. Coalesced, conflict-free.
        float areg[16];
        {
            float dv = dinv[min(j0 + lane, jmax)];   // pad rows: A is 0 anyway
#pragma unroll
            for (int g = 0; g < 16; ++g)
                areg[g] = Ach[(q * 16 + g) * 64 + lane] * dv;
        }
        __syncthreads();   // all areg reads done -> Ach reusable next bucket

        if (bkt < NBUCK - 1) {
            // FAST path: this wave covers rows rbase..rbase+31; 8-row
            // over-read stays < NN (j0<=99904 -> j0+32+39 <= 99975).
            const float4* xp = x4 + (size_t)(j0 + rbase) * 64 + lane;
            float4 buf[8];
#pragma unroll
            for (int k = 0; k < 8; ++k) buf[k] = xp[k * 64];
            xp += 512;
            for (int c = 0; c < 4; ++c) {        // 4 groups of 8 rows
#pragma unroll
                for (int jj = 0; jj < 8; ++jj) {
                    float4 xv = buf[jj];
                    buf[jj] = xp[jj * 64];       // reissue slot 8 rows ahead
#pragma unroll
                    for (int g = 0; g < 16; ++g) {
                        float aq = __int_as_float(__builtin_amdgcn_readlane(
                            __float_as_int(areg[g]), rbase + c * 8 + jj));
                        acc[g][0] = fmaf(aq, xv.x, acc[g][0]);
                        acc[g][1] = fmaf(aq, xv.y, acc[g][1]);
                        acc[g][2] = fmaf(aq, xv.z, acc[g][2]);
                        acc[g][3] = fmaf(aq, xv.w, acc[g][3]);
                    }
                }
                xp += 512;
            }
        } else {
            // TAIL bucket (one per grid): clamped depth-1 loop over 32 rows.
#pragma unroll 4
            for (int jj = 0; jj < 32; ++jj) {
                float4 xv = x4[(size_t)min(j0 + rbase + jj, jmax) * 64 + lane];
#pragma unroll
                for (int g = 0; g < 16; ++g) {
                    float aq = __int_as_float(__builtin_amdgcn_readlane(
                        __float_as_int(areg[g]), rbase + jj));
                    acc[g][0] = fmaf(aq, xv.x, acc[g][0]);
                    acc[g][1] = fmaf(aq, xv.y, acc[g][1]);
                    acc[g][2] = fmaf(aq, xv.z, acc[g][2]);
                    acc[g][3] = fmaf(aq, xv.w, acc[g][3]);
                }
            }
        }
    }

    // Combine row-halves once per block lifetime: 16 static-g rounds through
    // Ach (dead now). rh==1 waves publish acc[g]; rh==0 waves add.
    __syncthreads();
#pragma unroll
    for (int g = 0; g < 16; ++g) {
        if (rh == 1)
            Ach4[q * 64 + lane] = make_float4(acc[g][0], acc[g][1],
                                              acc[g][2], acc[g][3]);
        __syncthreads();
        if (rh == 0) {
            float4 v = Ach4[q * 64 + lane];
            acc[g][0] += v.x; acc[g][1] += v.y;
            acc[g][2] += v.z; acc[g][3] += v.w;
        }
        __syncthreads();
    }

    // write block partial (rh==0 waves): graphs q*16..+16, feats lane*4..+4
    if (rh == 0) {
        float* p = part + (size_t)blockIdx.x * (NG * DIMK);
#pragma unroll
        for (int g = 0; g < 16; ++g) {
            float4 wv = make_float4(acc[g][0], acc[g][1], acc[g][2], acc[g][3]);
            ((float4*)(p + (q * 16 + g) * DIMK))[lane] = wv;
        }
    }
}

// Merged tail: block g (64 blocks, 512 threads): 8 slice-strided coalesced
// sums over the partials (float4 per thread), LDS-fold, then S@W/cnt + bias.
__global__ __launch_bounds__(512) void k_tail(const float4* __restrict__ part,
        const float* __restrict__ W, const float* __restrict__ bias,
        const int* __restrict__ start, float* __restrict__ out, int nblk) {
    __shared__ __align__(16) float4 ls[8][64];   // 8 KB
    __shared__ float Sb[DIMK];
    const int tid = threadIdx.x, g = blockIdx.x;
    const int c4 = tid & 63;     // float4 col of graph row
    const int sl = tid >> 6;     // slice 0..7
    float4 s = make_float4(0.f, 0.f, 0.f, 0.f);
    for (int b = sl; b < nblk; b += 8) {
        float4 v = part[(size_t)b * 4096 + g * 64 + c4];
        s.x += v.x; s.y += v.y; s.z += v.z; s.w += v.w;
    }
    ls[sl][c4] = s;
    __syncthreads();
    if (sl == 0) {
        float4 t = ls[0][c4];
#pragma unroll
        for (int k = 1; k < 8; ++k) {
            float4 v = ls[k][c4];
            t.x += v.x; t.y += v.y; t.z += v.z; t.w += v.w;
        }
        Sb[c4 * 4 + 0] = t.x; Sb[c4 * 4 + 1] = t.y;
        Sb[c4 * 4 + 2] = t.z; Sb[c4 * 4 + 3] = t.w;
    }
    __syncthreads();
    if (tid < NC) {
        float sum = 0.f;
#pragma unroll 8
        for (int d = 0; d < DIMK; ++d)
            sum = fmaf(Sb[d], W[d * NC + tid], sum);
        float cn = (float)max(start[g + 1] - start[g], 1);
        out[g * NC + tid] = sum / cn + bias[tid];
    }
}

extern "C" void kernel_launch(void* const* d_in, const int* in_sizes, int n_in,
                              void* d_out, int out_size, void* d_ws, size_t ws_size,
                              hipStream_t stream) {
    const float* x    = (const float*)d_in[0];
    const float* W    = (const float*)d_in[1];
    const float* bias = (const float*)d_in[2];
    const void*  ei   = d_in[3];
    const void*  batch= d_in[4];
    float* out = (float*)d_out;

    char* ws = (char*)d_ws;
    unsigned int* rec  = (unsigned int*)(ws + OFF_REC);
    unsigned int* degp = (unsigned int*)(ws + OFF_REC);    // overlay (dead before rec)
    float* dinv  = (float*)(ws + OFF_DINV);
    int*   btot  = (int*)(ws + OFF_BTOT);
    int*   start = (int*)(ws + OFF_START);
    int*   ctrl  = (int*)(ws + OFF_CTRL);
    float* part  = (float*)(ws + OFF_PART);
    // overlays inside part region (dead before k_fused writes partials):
    unsigned int* nodeinfo = (unsigned int*)(ws + OFF_NODEI);
    int*   cnt   = (int*)(ws + OFF_CNT);
    int*   exc   = (int*)(ws + OFF_EXC);

    // grid sized to workspace (ws in [43.5, 54.6) MB -> grid ~410-512)
    long avail = (long)(ws_size - OFF_PART) / 65536;
    int grid = (int)avail;
    if (grid > MAXG) grid = MAXG;
    if (grid < 64) grid = 64;

    k_pre  <<<768, 256, 0, stream>>>(ei, degp, cnt);
    k_mid  <<<1808, 512, 0, stream>>>(degp, nodeinfo, dinv, batch, ei, start,
                                      cnt, exc, btot);
    k_place<<<NB1, 256, 0, stream>>>(ei, nodeinfo, exc, rec, ctrl);
    k_fused<<<grid, 512, 0, stream>>>(x, dinv, batch, ei, rec, btot, part, ctrl);
    k_tail <<<NG, 512, 0, stream>>>((const float4*)part, W, bias, start, out, grid);
}

// Round 23
// 197.068 us; speedup vs baseline: 1.1559x; 1.1124x over previous
//
#include <hip/hip_runtime.h>

// Problem constants (fixed by the reference)
#define NN    100000   // nodes
#define NE    3200000  // edges
#define DIMK  256      // feature dim
#define NC    32       // classes
#define NG    64       // graphs

#define ROWS   64      // nodes per src-bucket
#define NBUCK  1563    // ceil(NN/64)
#define CAP    2432    // per-bucket record capacity (mean 2047, sigma ~45 -> +8.5 sigma)
#define NB1    512     // edge chunks for bucketing (NE/NB1 = 6250 exact)
#define EPB    6250    // edges per bucketing block
#define MAXG   512     // cap on k_fused blocks (2/CU)

// Workspace layout (bytes). Fixed region = 16.66 MB; partials sized from ws.
// nodeinfo/cnt/exc overlay the FRONT of the partial region (dead before k_fused).
static constexpr size_t OFF_REC    = 0;           // [NBUCK*CAP] u32 = 15,204,864
                                                  // (first 12.8 MB doubles as deg partials)
static constexpr size_t OFF_DINV   = 15204864;    // [NN] f32 = 400,000
static constexpr size_t OFF_BTOT   = 15604864;    // [NBUCK] int (pad 8192)
static constexpr size_t OFF_START  = 15613056;    // [NG+1] int (pad 512)
static constexpr size_t OFF_CTRL   = 15613568;    // int[32] (pad 128)
static constexpr size_t OFF_P2     = 15613696;    // (spare) 1 MB
static constexpr size_t OFF_PART   = 16662272;    // [grid][NG*DIMK] f32 (64 KB each)
// overlays (dead before k_fused writes partials):
static constexpr size_t OFF_NODEI  = OFF_PART;              // [NN] u32: (deg<<6)|batch
static constexpr size_t OFF_CNT    = OFF_PART + 400000;     // [NBUCK*NB1] int = 3,201,024
static constexpr size_t OFF_EXC    = OFF_PART + 3601024;    // [NBUCK*NB1] int (ends +6.8MB)

__device__ __forceinline__ int idx_at(const void* p, long i, bool i64) {
    return i64 ? (int)((const long long*)p)[i] : ((const int*)p)[i];
}

// int64 vs int32: high words of the first int64 entries are all zero.
// For genuine int32 src indices in [0,100000), P(false positive) ~ 1e-30.
__device__ __forceinline__ bool detect_i64(const void* ei) {
    const int* w = (const int*)ei;
    return (w[1] == 0) & (w[3] == 0) & (w[5] == 0) &
           (w[7] == 0) & (w[9] == 0) & (w[11] == 0);
}

// Merged edge pass 1.
// Blocks 0..255: degree histogram halves (u8 LDS counters; max deg ~70 << 255).
// Blocks 256..767: per-(bucket,chunk) counts via LDS counters.
__global__ __launch_bounds__(256) void k_pre(const void* __restrict__ ei,
        unsigned int* __restrict__ parts, int* __restrict__ cnt) {
    __shared__ unsigned int h[12500];   // 50 KB
    const bool i64 = detect_i64(ei);
    const int b = blockIdx.x;
    if (b < 256) {
        const int hh = b >> 7;
        const int sl = b & 127;
        const int lo = hh * 50000, hi = lo + 50000;
        for (int t = threadIdx.x; t < 12500; t += 256) h[t] = 0u;
        __syncthreads();
        const int e0 = sl * 25000;
        for (int e = e0 + threadIdx.x; e < e0 + 25000; e += 256) {
            int d = idx_at(ei, (long)NE + e, i64);
            if (d >= lo && d < hi) {
                int r = d - lo;
                atomicAdd(&h[r >> 2], 1u << ((r & 3) * 8));
            }
        }
        __syncthreads();
        for (int t = threadIdx.x; t < 12500; t += 256)
            parts[(size_t)b * 12500 + t] = h[t];
    } else {
        const int k = b - 256;          // 0..511
        for (int t = threadIdx.x; t < NBUCK; t += 256) h[t] = 0u;
        __syncthreads();
        const int e0 = k * EPB;
        for (int e = e0 + threadIdx.x; e < e0 + EPB; e += 256) {
            int s = idx_at(ei, e, i64);
            atomicAdd(&h[s >> 6], 1u);
        }
        __syncthreads();
        for (int t = threadIdx.x; t < NBUCK; t += 256)
            cnt[t * NB1 + k] = (int)h[t];
    }
}

// Merged node/offset pass (512 threads).
// Blocks 0..48: degree reduce -> dinv AND nodeinfo = (deg<<6)|batch[node].
// Blocks 49..244: graph start offsets from sorted batch.
// Blocks 245..1807: per-bucket exclusive scan of its 512 chunk counts.
__global__ __launch_bounds__(512) void k_mid(const unsigned int* __restrict__ parts,
        unsigned int* __restrict__ nodeinfo, float* __restrict__ dinv,
        const void* __restrict__ batch, const void* __restrict__ ei,
        int* __restrict__ start, const int* __restrict__ cnt,
        int* __restrict__ exc, int* __restrict__ btot) {
    __shared__ int s[512];
    const int b = blockIdx.x;
    const int t = threadIdx.x;
    if (b < 49) {
        const bool i64 = detect_i64(ei);
        int i = b * 512 + t;            // word index 0..24999
        if (i >= 25000) return;
        int h = (i >= 12500) ? 1 : 0;
        int w = i - h * 12500;
        int c0 = 0, c1 = 0, c2 = 0, c3 = 0;
        const unsigned int* base = parts + (size_t)(h * 128) * 12500 + w;
#pragma unroll 4
        for (int q = 0; q < 128; ++q) {
            unsigned int v = base[(size_t)q * 12500];
            c0 += v & 255u; c1 += (v >> 8) & 255u; c2 += (v >> 16) & 255u; c3 += v >> 24;
        }
        int node = h * 50000 + w * 4;
        dinv[node]     = 1.0f / sqrtf((float)(1 + c0));
        dinv[node + 1] = 1.0f / sqrtf((float)(1 + c1));
        dinv[node + 2] = 1.0f / sqrtf((float)(1 + c2));
        dinv[node + 3] = 1.0f / sqrtf((float)(1 + c3));
        nodeinfo[node]     = ((unsigned)(1 + c0) << 6) | (unsigned)idx_at(batch, node, i64);
        nodeinfo[node + 1] = ((unsigned)(1 + c1) << 6) | (unsigned)idx_at(batch, node + 1, i64);
        nodeinfo[node + 2] = ((unsigned)(1 + c2) << 6) | (unsigned)idx_at(batch, node + 2, i64);
        nodeinfo[node + 3] = ((unsigned)(1 + c3) << 6) | (unsigned)idx_at(batch, node + 3, i64);
    } else if (b < 245) {
        const bool i64 = detect_i64(ei);
        int i = (b - 49) * 512 + t;
        if (i >= NN) return;
        int bi = idx_at(batch, i, i64);
        int bp = (i == 0) ? -1 : idx_at(batch, i - 1, i64);
        for (int g = bp + 1; g <= bi; ++g) start[g] = i;
        if (i == NN - 1)
            for (int g = bi + 1; g <= NG; ++g) start[g] = NN;
    } else {
        const int bkt = b - 245;        // 0..1562
        int v = cnt[bkt * NB1 + t];
        s[t] = v;
        __syncthreads();
        for (int off = 1; off < 512; off <<= 1) {
            int u = (t >= off) ? s[t - off] : 0;
            __syncthreads();
            s[t] += u;
            __syncthreads();
        }
        exc[bkt * NB1 + t] = bkt * CAP + (s[t] - v);
        if (t == 511) btot[bkt] = s[511];
    }
}

// Place 4-byte edge records: (deg[dst] << 12) | (batch[dst]*64 + (src&63)).
// ONE random 4B gather per edge (nodeinfo fuses deg+batch).
// TRANSPOSED A index (graph-major). Also zeroes the k_fused work counter.
__global__ __launch_bounds__(256) void k_place(const void* __restrict__ ei,
        const unsigned int* __restrict__ nodeinfo,
        const int* __restrict__ exc, unsigned int* __restrict__ rec,
        int* __restrict__ ctrl) {
    __shared__ unsigned int lc[NBUCK];
    __shared__ int lbase[NBUCK];
    const bool i64 = detect_i64(ei);
    const int k = blockIdx.x;
    if (k == 0 && threadIdx.x == 0) ctrl[1] = 0;
    for (int t = threadIdx.x; t < NBUCK; t += 256) {
        lc[t] = 0u;
        lbase[t] = exc[t * NB1 + k];
    }
    __syncthreads();
    const int e0 = k * EPB;
    for (int e = e0 + threadIdx.x; e < e0 + EPB; e += 256) {
        int s = idx_at(ei, e, i64);
        int d = idx_at(ei, (long)NE + e, i64);
        unsigned int ni = nodeinfo[d];
        unsigned int deg = min(ni >> 6, 1048575u);
        unsigned int g = ni & 63u;
        int b = s >> 6;
        unsigned int r = atomicAdd(&lc[b], 1u);
        rec[lbase[b] + (int)r] = (deg << 12) | (g * 64 + (unsigned)(s & 63));
    }
}

// Fused persistent kernel (frozen r19 form - best measured, 89us). 512
// threads, 16.5 KB LDS, launch_bounds(512,2) (= min 2 BLOCKS/CU, CUDA
// semantics verified r8-r11 -> VGPR cap 128). Per bucket: build A'-chunk
// TRANSPOSED [graph][row] via LDS atomics; pull A to registers (readlane,
// fused dinv row scale); x from global with pointer-based prefetch. Eleven
// structural variants (r12-r22: deeper prefetch, LDS staging, async DMA,
// wave remaps, work splits, lockstep) all regressed or tied - this is the
// structural equilibrium (~50% VALU, latency-bound depth-1 loads).
__global__ __launch_bounds__(512, 2) void k_fused(
        const float* __restrict__ x, const float* __restrict__ dinv,
        const void* __restrict__ batch, const void* __restrict__ ei,
        const unsigned int* __restrict__ rec, const int* __restrict__ btot,
        float* __restrict__ part, int* __restrict__ ctrl) {
    __shared__ __align__(16) float Ach[64 * ROWS];    // 16 KB, [graph][row]
    __shared__ int sbkt;
    const bool i64 = detect_i64(ei);
    const int tid  = threadIdx.x;
    const int gi   = tid >> 6;     // wave id = graph group 0..7
    const int lane = tid & 63;     // row for areg; features lane*4..+4 for x

    float acc[8][4];
#pragma unroll
    for (int g = 0; g < 8; ++g)
#pragma unroll
        for (int d = 0; d < 4; ++d) acc[g][d] = 0.0f;

    const float4* x4 = (const float4*)x;
    float4* Ach4 = (float4*)Ach;
    const float4 z4 = make_float4(0.f, 0.f, 0.f, 0.f);
    const int jmax = NN - 1;

    for (;;) {
        if (tid == 0) sbkt = atomicAdd(&ctrl[1], 1);
        __syncthreads();
        const int bkt = sbkt;
        if (bkt >= NBUCK) break;
        const int j0 = bkt * ROWS;

        // zero Ach (conflict-free linear float4)
        Ach4[tid] = z4;
        Ach4[tid + 512] = z4;
        __syncthreads();
        // seed self-loop: Ach[batch[j]][r] = dinv[j]; areg scale -> dinv^2
        if (tid < ROWS) {
            int j = j0 + tid;
            if (j < NN) Ach[idx_at(batch, j, i64) * 64 + tid] = dinv[j];
        }
        __syncthreads();
        // replay edge records into Ach via LDS atomics (index = g*64+row)
        {
            const int rb = bkt * CAP;
            const int re = rb + btot[bkt];
            for (int r = rb + tid; r < re; r += 512) {
                unsigned int q = rec[r];
                float val = 1.0f / sqrtf((float)(q >> 12));   // == dinv[dst] bits
                atomicAdd(&Ach[q & 4095u], val);
            }
        }
        __syncthreads();
        // pull A into registers (fused dinv[src] row scale); coalesced reads
        float areg[8];
        {
            float dv = dinv[min(j0 + lane, jmax)];   // pad rows: A is 0 anyway
#pragma unroll
            for (int q = 0; q < 8; ++q)
                areg[q] = Ach[(gi * 8 + q) * 64 + lane] * dv;
        }
        __syncthreads();   // all areg reads done -> Ach reusable next bucket

        if (bkt < NBUCK - 1) {
            // FAST path: rows j0..j0+63 valid; over-read stays < NN.
            const float4* xp = x4 + (size_t)j0 * 64 + lane;
            float4 buf[8];
#pragma unroll
            for (int k = 0; k < 8; ++k) buf[k] = xp[k * 64];
            xp += 512;
            for (int c = 0; c < 8; ++c) {        // 8 groups of 8 rows
#pragma unroll
                for (int jj = 0; jj < 8; ++jj) {
                    float4 xv = buf[jj];
                    buf[jj] = xp[jj * 64];       // reissue slot 8 rows ahead
#pragma unroll
                    for (int q = 0; q < 8; ++q) {
                        float aq = __int_as_float(__builtin_amdgcn_readlane(
                            __float_as_int(areg[q]), c * 8 + jj));
                        acc[q][0] = fmaf(aq, xv.x, acc[q][0]);
                        acc[q][1] = fmaf(aq, xv.y, acc[q][1]);
                        acc[q][2] = fmaf(aq, xv.z, acc[q][2]);
                        acc[q][3] = fmaf(aq, xv.w, acc[q][3]);
                    }
                }
                xp += 512;
            }
        } else {
            // TAIL bucket (one per grid): clamped depth-1 loop.
            float4 xv = x4[(size_t)min(j0, jmax) * 64 + lane];
#pragma unroll 4
            for (int jj = 0; jj < ROWS; ++jj) {
                float4 xn = x4[(size_t)min(j0 + jj + 1, jmax) * 64 + lane];
#pragma unroll
                for (int q = 0; q < 8; ++q) {
                    float aq = __int_as_float(__builtin_amdgcn_readlane(
                        __float_as_int(areg[q]), jj));
                    acc[q][0] = fmaf(aq, xv.x, acc[q][0]);
                    acc[q][1] = fmaf(aq, xv.y, acc[q][1]);
                    acc[q][2] = fmaf(aq, xv.z, acc[q][2]);
                    acc[q][3] = fmaf(aq, xv.w, acc[q][3]);
                }
                xv = xn;
            }
        }
    }

    // write block partial: graphs gi*8..+8, features lane*4..+4 (all static)
    float* p = part + (size_t)blockIdx.x * (NG * DIMK);
#pragma unroll
    for (int g = 0; g < 8; ++g) {
        float4 w = make_float4(acc[g][0], acc[g][1], acc[g][2], acc[g][3]);
        ((float4*)(p + (gi * 8 + g) * DIMK))[lane] = w;
    }
}

// Merged tail: block g (64 blocks, 512 threads): 8 slice-strided coalesced
// sums over the partials (float4 per thread), LDS-fold, then S@W/cnt + bias.
__global__ __launch_bounds__(512) void k_tail(const float4* __restrict__ part,
        const float* __restrict__ W, const float* __restrict__ bias,
        const int* __restrict__ start, float* __restrict__ out, int nblk) {
    __shared__ __align__(16) float4 ls[8][64];   // 8 KB
    __shared__ float Sb[DIMK];
    const int tid = threadIdx.x, g = blockIdx.x;
    const int c4 = tid & 63;     // float4 col of graph row
    const int sl = tid >> 6;     // slice 0..7
    float4 s = make_float4(0.f, 0.f, 0.f, 0.f);
    for (int b = sl; b < nblk; b += 8) {
        float4 v = part[(size_t)b * 4096 + g * 64 + c4];
        s.x += v.x; s.y += v.y; s.z += v.z; s.w += v.w;
    }
    ls[sl][c4] = s;
    __syncthreads();
    if (sl == 0) {
        float4 t = ls[0][c4];
#pragma unroll
        for (int k = 1; k < 8; ++k) {
            float4 v = ls[k][c4];
            t.x += v.x; t.y += v.y; t.z += v.z; t.w += v.w;
        }
        Sb[c4 * 4 + 0] = t.x; Sb[c4 * 4 + 1] = t.y;
        Sb[c4 * 4 + 2] = t.z; Sb[c4 * 4 + 3] = t.w;
    }
    __syncthreads();
    if (tid < NC) {
        float sum = 0.f;
#pragma unroll 8
        for (int d = 0; d < DIMK; ++d)
            sum = fmaf(Sb[d], W[d * NC + tid], sum);
        float cn = (float)max(start[g + 1] - start[g], 1);
        out[g * NC + tid] = sum / cn + bias[tid];
    }
}

extern "C" void kernel_launch(void* const* d_in, const int* in_sizes, int n_in,
                              void* d_out, int out_size, void* d_ws, size_t ws_size,
                              hipStream_t stream) {
    const float* x    = (const float*)d_in[0];
    const float* W    = (const float*)d_in[1];
    const float* bias = (const float*)d_in[2];
    const void*  ei   = d_in[3];
    const void*  batch= d_in[4];
    float* out = (float*)d_out;

    char* ws = (char*)d_ws;
    unsigned int* rec  = (unsigned int*)(ws + OFF_REC);
    unsigned int* degp = (unsigned int*)(ws + OFF_REC);    // overlay (dead before rec)
    float* dinv  = (float*)(ws + OFF_DINV);
    int*   btot  = (int*)(ws + OFF_BTOT);
    int*   start = (int*)(ws + OFF_START);
    int*   ctrl  = (int*)(ws + OFF_CTRL);
    float* part  = (float*)(ws + OFF_PART);
    // overlays inside part region (dead before k_fused writes partials):
    unsigned int* nodeinfo = (unsigned int*)(ws + OFF_NODEI);
    int*   cnt   = (int*)(ws + OFF_CNT);
    int*   exc   = (int*)(ws + OFF_EXC);

    // grid sized to workspace (ws in [43.5, 54.6) MB -> grid ~410-512)
    long avail = (long)(ws_size - OFF_PART) / 65536;
    int grid = (int)avail;
    if (grid > MAXG) grid = MAXG;
    if (grid < 64) grid = 64;

    k_pre  <<<768, 256, 0, stream>>>(ei, degp, cnt);
    k_mid  <<<1808, 512, 0, stream>>>(degp, nodeinfo, dinv, batch, ei, start,
                                      cnt, exc, btot);
    k_place<<<NB1, 256, 0, stream>>>(ei, nodeinfo, exc, rec, ctrl);
    k_fused<<<grid, 512, 0, stream>>>(x, dinv, batch, ei, rec, btot, part, ctrl);
    k_tail <<<NG, 512, 0, stream>>>((const float4*)part, W, bias, start, out, grid);
}